// Round 6
// baseline (456.015 us; speedup 1.0000x reference)
//
#include <hip/hip_runtime.h>
#include <hip/hip_fp16.h>

#define DIM 256
#define MARGIN 2.25e-4f
#define WLCAP 262144

typedef __bf16 bf8v __attribute__((ext_vector_type(8)));
typedef float f4v __attribute__((ext_vector_type(4)));

__device__ inline unsigned short f2bf(float x) {
    unsigned u = __float_as_uint(x);
    u += 0x7fffu + ((u >> 16) & 1u);   // RNE
    return (unsigned short)(u >> 16);
}

// ---------------- transpose z [8,256,32,32] -> zf [8192,256] fp32 + zb bf16 ----------------
__global__ __launch_bounds__(256) void k_zprep(const float* __restrict__ z,
                                               float* __restrict__ zf,
                                               unsigned short* __restrict__ zb) {
    __shared__ float t[32][33];
    const int hw0 = blockIdx.x * 32;
    const int d0  = blockIdx.y * 32;
    const int b   = blockIdx.z;
    const int tx = threadIdx.x & 31, ty = threadIdx.x >> 5;
#pragma unroll
    for (int i = 0; i < 4; i++) {
        const int d = d0 + ty + 8 * i;
        t[ty + 8 * i][tx] = z[(b * 256 + d) * 1024 + hw0 + tx];
    }
    __syncthreads();
#pragma unroll
    for (int i = 0; i < 4; i++) {
        const int hw = hw0 + ty + 8 * i;
        const float v = t[tx][ty + 8 * i];
        const size_t o = (size_t)(b * 1024 + hw) * DIM + d0 + tx;
        zf[o] = v;
        zb[o] = f2bf(v);
    }
}

// ---------------- emb -> eb bf16 + enorm; also zero worklist counter ----------------
__global__ __launch_bounds__(256) void k_eprep(const float* __restrict__ emb,
                                               unsigned short* __restrict__ eb,
                                               float* __restrict__ enorm,
                                               int* __restrict__ gcnt) {
    if (blockIdx.x == 0 && threadIdx.x == 0) gcnt[0] = 0;
    const int wave = threadIdx.x >> 6, lane = threadIdx.x & 63;
    const int row = blockIdx.x * 4 + wave;
    const float4 v = *(const float4*)(emb + (size_t)row * DIM + lane * 4);
    ushort4 o;
    o.x = f2bf(v.x); o.y = f2bf(v.y); o.z = f2bf(v.z); o.w = f2bf(v.w);
    *(ushort4*)(eb + (size_t)row * DIM + lane * 4) = o;
    float s = v.x * v.x + v.y * v.y + v.z * v.z + v.w * v.w;
#pragma unroll
    for (int m = 1; m < 64; m <<= 1) s += __shfl_xor(s, m, 64);
    if (lane == 0) enorm[row] = s;
}

// ---------------- rownorm over zf ----------------
__global__ __launch_bounds__(256) void k_rownorm(const float* __restrict__ src,
                                                 float* __restrict__ dst) {
    const int wave = threadIdx.x >> 6, lane = threadIdx.x & 63;
    const int row = blockIdx.x * 4 + wave;
    const float4 v = *(const float4*)(src + (size_t)row * DIM + lane * 4);
    float s = v.x * v.x + v.y * v.y + v.z * v.z + v.w * v.w;
#pragma unroll
    for (int m = 1; m < 64; m <<= 1) s += __shfl_xor(s, m, 64);
    if (lane == 0) dst[row] = s;
}

// ---------------- LDS-free bf16 MFMA scoring ----------------
// Block: 64 rows x 256 cols; wave wc covers 64 rows x 64 cols.
// Group g = by*16 + wc*4 + (m15>>2): codes by*256 + wc*64 + ct*16 + (m15>>2)*4 + l
// pvalh[row][g] = fp16( min over the group's 16 codes of (en - 2*dot_bf16) )
__global__ __launch_bounds__(256) void k_score(
        const unsigned short* __restrict__ zb, const unsigned short* __restrict__ eb,
        const float* __restrict__ enorm, unsigned short* __restrict__ pvalh) {
    __shared__ unsigned short sm[64 * 16];   // 2 KB
    const int row0 = blockIdx.x * 64;
    const int col0 = blockIdx.y * 256;
    const int t = threadIdx.x;
    const int lane = t & 63;
    const int wc = t >> 6;
    const int q = lane >> 4, m15 = lane & 15;

    f4v acc[4][4];
#pragma unroll
    for (int rt = 0; rt < 4; rt++)
#pragma unroll
        for (int ct = 0; ct < 4; ct++) acc[rt][ct] = (f4v){0.f, 0.f, 0.f, 0.f};

    const unsigned short* a0 = zb + (size_t)(row0 + m15) * DIM + q * 8;
    const unsigned short* b0 = eb + (size_t)(col0 + wc * 64 + m15) * DIM + q * 8;

#pragma unroll
    for (int kk = 0; kk < DIM; kk += 32) {
        bf8v af[4], bfv[4];
#pragma unroll
        for (int rt = 0; rt < 4; rt++)
            af[rt] = *(const bf8v*)(a0 + (size_t)rt * 16 * DIM + kk);
#pragma unroll
        for (int ct = 0; ct < 4; ct++)
            bfv[ct] = *(const bf8v*)(b0 + (size_t)ct * 16 * DIM + kk);
#pragma unroll
        for (int rt = 0; rt < 4; rt++)
#pragma unroll
            for (int ct = 0; ct < 4; ct++)
                acc[rt][ct] = __builtin_amdgcn_mfma_f32_16x16x32_bf16(af[rt], bfv[ct], acc[rt][ct], 0, 0, 0);
    }

    // epilogue: s = en - 2*dot (approx, filter-only); fp32 group-min, fp16 store
    float en_l[4];
#pragma unroll
    for (int ct = 0; ct < 4; ct++) en_l[ct] = enorm[col0 + wc * 64 + ct * 16 + m15];

    const int g_local = wc * 4 + (m15 >> 2);
#pragma unroll
    for (int rt = 0; rt < 4; rt++) {
        float sv[4];
#pragma unroll
        for (int j = 0; j < 4; j++) {
            float s = fmaf(-2.f, acc[rt][0][j], en_l[0]);
#pragma unroll
            for (int ct = 1; ct < 4; ct++)
                s = fminf(s, fmaf(-2.f, acc[rt][ct][j], en_l[ct]));
            sv[j] = s;
        }
        // butterfly over l = m15&3 (xor 1, 2)
#pragma unroll
        for (int m = 1; m <= 2; m <<= 1)
#pragma unroll
            for (int j = 0; j < 4; j++)
                sv[j] = fminf(sv[j], __shfl_xor(sv[j], m, 64));
        if ((m15 & 3) == 0) {
            const int rbase = rt * 16 + q * 4;
#pragma unroll
            for (int j = 0; j < 4; j++)
                sm[(rbase + j) * 16 + g_local] = __half_as_ushort(__float2half_rn(sv[j]));
        }
    }
    __syncthreads();
    if (t < 128) {
        const uint4 v = *(const uint4*)&sm[t * 8];
        *(uint4*)&pvalh[(size_t)(row0 + (t >> 1)) * 1024 + blockIdx.y * 16 + (t & 1) * 8] = v;
    }
}

// ---------------- flag: per row, min over 1024 group-mins; append flagged to worklist ------------
__global__ __launch_bounds__(256) void k_flag(const unsigned short* __restrict__ pvalh,
                                              unsigned long long* __restrict__ best64,
                                              int* __restrict__ wl, int* __restrict__ gcnt) {
    const int row = blockIdx.x;
    const int t = threadIdx.x;
    const int lane = t & 63, w = t >> 6;
    __shared__ float wmin[4];
    __shared__ int lcnt, lbase;
    __shared__ int llist[1024];
    if (t == 0) { lcnt = 0; best64[row] = 0xFFFFFFFFFFFFFFFFULL; }
    const __half* p = (const __half*)(pvalh + (size_t)row * 1024 + t * 4);
    float v[4];
#pragma unroll
    for (int k = 0; k < 4; k++) v[k] = __half2float(p[k]);
    float mn = fminf(fminf(v[0], v[1]), fminf(v[2], v[3]));
#pragma unroll
    for (int m = 1; m < 64; m <<= 1) mn = fminf(mn, __shfl_xor(mn, m, 64));
    if (lane == 0) wmin[w] = mn;
    __syncthreads();
    const float g = fminf(fminf(wmin[0], wmin[1]), fminf(wmin[2], wmin[3])) + MARGIN;
#pragma unroll
    for (int k = 0; k < 4; k++) {
        if (v[k] <= g) {
            const int pos = atomicAdd(&lcnt, 1);
            llist[pos] = (row << 10) | (t * 4 + k);
        }
    }
    __syncthreads();
    if (t == 0) lbase = atomicAdd(gcnt, lcnt);
    __syncthreads();
    for (int i = t; i < lcnt; i += 256) {
        const int d = lbase + i;
        if (d < WLCAP) wl[d] = llist[i];
    }
}

// ---------------- rescore: exact fp32 re-score of flagged 16-code (strided) groups --------------
__global__ __launch_bounds__(256) void k_rescore(
        const float* __restrict__ zf, const float* __restrict__ emb,
        const float* __restrict__ znorm, const float* __restrict__ enorm,
        const int* __restrict__ wl, const int* __restrict__ gcnt,
        unsigned long long* __restrict__ best64) {
    const int count = min(gcnt[0], WLCAP);
    const int t = threadIdx.x;
    const int lane16 = t & 15, codei = t >> 4;
    for (int item = blockIdx.x; item < count; item += gridDim.x) {
        const int e = wl[item];
        const int row = e >> 10, g = e & 1023;
        // group membership: codes = (g>>4)*256 + ((g>>2)&3)*64 + ct*16 + (g&3)*4 + l
        const int cbase = ((g >> 4) << 8) + (((g >> 2) & 3) << 6) + ((g & 3) << 2);
        const int code = cbase + ((codei >> 2) << 4) + (codei & 3);
        const float* zp = zf + (size_t)row * DIM + lane16 * 16;
        const float* ep = emb + (size_t)code * DIM + lane16 * 16;
        float d = 0.f;
#pragma unroll
        for (int k = 0; k < 16; k += 4) {
            const float4 ev = *(const float4*)(ep + k);
            const float4 zv = *(const float4*)(zp + k);
            d = fmaf(zv.x, ev.x, d);
            d = fmaf(zv.y, ev.y, d);
            d = fmaf(zv.z, ev.z, d);
            d = fmaf(zv.w, ev.w, d);
        }
#pragma unroll
        for (int m = 1; m <= 8; m <<= 1) d += __shfl_xor(d, m, 64);
        if (lane16 == 0) {
            const float tt = znorm[row] + enorm[code];
            const float s = tt - 2.0f * d;   // exact fp32 semantics
            const unsigned long long key =
                ((unsigned long long)__float_as_uint(s) << 32) | (unsigned)code;
            atomicMin(&best64[row], key);
        }
    }
}

// ---------------- out_idx from best64 ----------------
__global__ __launch_bounds__(256) void k_finalidx(const unsigned long long* __restrict__ best64,
                                                  float* __restrict__ out_idx) {
    const int i = blockIdx.x * 256 + threadIdx.x;
    out_idx[i] = (float)(unsigned)(best64[i] & 0xFFFFFFFFULL);
}

// ---------------- gather z_q (NCHW) + loss partials ----------------
__global__ __launch_bounds__(256) void k_gather(const float* __restrict__ emb,
                                                const float* __restrict__ zf,
                                                const unsigned long long* __restrict__ best64,
                                                float* __restrict__ zq,
                                                float* __restrict__ loss_part) {
    __shared__ float t[32][33];
    const int hw0 = blockIdx.x * 32;
    const int c0  = blockIdx.y * 32;
    const int b   = blockIdx.z;
    const int tx = threadIdx.x & 31, ty = threadIdx.x >> 5;
    float lsum = 0.f;
#pragma unroll
    for (int i = 0; i < 4; i++) {
        const int hh = ty + 8 * i;
        const int n = b * 1024 + hw0 + hh;
        const int id = (int)(best64[n] & 0xFFFFFFFFULL);
        const float q = emb[(size_t)id * DIM + c0 + tx];
        const float zv = zf[(size_t)n * DIM + c0 + tx];
        const float d = q - zv;
        lsum += d * d;
        t[hh][tx] = q;
    }
    __syncthreads();
#pragma unroll
    for (int i = 0; i < 4; i++) {
        const int c = c0 + ty + 8 * i;
        zq[(size_t)(b * 256 + c) * 1024 + hw0 + tx] = t[tx][ty + 8 * i];
    }
#pragma unroll
    for (int m = 1; m < 64; m <<= 1) lsum += __shfl_xor(lsum, m, 64);
    __shared__ float wsum[4];
    const int lane = threadIdx.x & 63, w = threadIdx.x >> 6;
    if (lane == 0) wsum[w] = lsum;
    __syncthreads();
    if (threadIdx.x == 0) {
        const int bid = (blockIdx.z * gridDim.y + blockIdx.y) * gridDim.x + blockIdx.x;
        loss_part[bid] = wsum[0] + wsum[1] + wsum[2] + wsum[3];
    }
}

// ---------------- finalize loss ----------------
__global__ __launch_bounds__(256) void k_final(const float* __restrict__ loss_part,
                                               float* __restrict__ out_loss) {
    float s = 0.f;
    for (int i = threadIdx.x; i < 2048; i += 256) s += loss_part[i];
#pragma unroll
    for (int m = 1; m < 64; m <<= 1) s += __shfl_xor(s, m, 64);
    __shared__ float wsum[4];
    const int lane = threadIdx.x & 63, w = threadIdx.x >> 6;
    if (lane == 0) wsum[w] = s;
    __syncthreads();
    if (threadIdx.x == 0) {
        out_loss[0] = 1.25f * (wsum[0] + wsum[1] + wsum[2] + wsum[3]) / 2097152.0f;
    }
}

extern "C" void kernel_launch(void* const* d_in, const int* in_sizes, int n_in,
                              void* d_out, int out_size, void* d_ws, size_t ws_size,
                              hipStream_t stream) {
    const float* z   = (const float*)d_in[0];   // [8,256,32,32]
    const float* emb = (const float*)d_in[1];   // [16384,256]
    float* out = (float*)d_out;
    float* ws  = (float*)d_ws;

    // ws layout (float-slot offsets):
    float*              zf    = ws;                                   // 2,097,152  (8 MB)
    unsigned short*     pvalh = (unsigned short*)(ws + 2097152);      // 8M halves  (16 MB)
    unsigned short*     zb    = (unsigned short*)(ws + 6291456);      // 2M halves  (4 MB)
    unsigned short*     eb    = (unsigned short*)(ws + 7340032);      // 4M halves  (8 MB)
    float*              enorm = ws + 9437184;                         // 16,384
    float*              znorm = ws + 9453568;                         // 8,192
    unsigned long long* best64= (unsigned long long*)(ws + 9461760);  // 8192 × 8 B
    int*                wl    = (int*)(ws + 9478144);                 // 262,144
    int*                gcnt  = (int*)(ws + 9740288);                 // 8
    float*              lossp = ws + 9740296;                         // 2,048
    // total ≈ 39 MB

    float* zq       = out;                   // [8,256,32,32] NCHW
    float* out_loss = out + 2097152;         // scalar
    float* out_idx  = out + 2097153;         // [8192] as float32

    k_zprep<<<dim3(32, 8, 8), 256, 0, stream>>>(z, zf, zb);
    k_eprep<<<dim3(4096), 256, 0, stream>>>(emb, eb, enorm, gcnt);
    k_rownorm<<<dim3(2048), 256, 0, stream>>>(zf, znorm);
    k_score<<<dim3(128, 64), 256, 0, stream>>>(zb, eb, enorm, pvalh);
    k_flag<<<dim3(8192), 256, 0, stream>>>(pvalh, best64, wl, gcnt);
    k_rescore<<<dim3(2048), 256, 0, stream>>>(zf, emb, znorm, enorm, wl, gcnt, best64);
    k_finalidx<<<dim3(32), 256, 0, stream>>>(best64, out_idx);
    k_gather<<<dim3(32, 8, 8), 256, 0, stream>>>(emb, zf, best64, zq, lossp);
    k_final<<<1, 256, 0, stream>>>(lossp, out_loss);
}

// Round 7
// 454.667 us; speedup vs baseline: 1.0030x; 1.0030x over previous
//
#include <hip/hip_runtime.h>
#include <hip/hip_fp16.h>

#define DIM 256
#define MARGIN 2.25e-4f
#define WLCAP 262144

typedef __bf16 bf8v __attribute__((ext_vector_type(8)));
typedef float f4v __attribute__((ext_vector_type(4)));

__device__ inline unsigned short f2bf(float x) {
    unsigned u = __float_as_uint(x);
    u += 0x7fffu + ((u >> 16) & 1u);   // RNE
    return (unsigned short)(u >> 16);
}

// ---------------- transpose z [8,256,32,32] -> zf [8192,256] fp32 + zb bf16 ----------------
__global__ __launch_bounds__(256) void k_zprep(const float* __restrict__ z,
                                               float* __restrict__ zf,
                                               unsigned short* __restrict__ zb) {
    __shared__ float t[32][33];
    const int hw0 = blockIdx.x * 32;
    const int d0  = blockIdx.y * 32;
    const int b   = blockIdx.z;
    const int tx = threadIdx.x & 31, ty = threadIdx.x >> 5;
#pragma unroll
    for (int i = 0; i < 4; i++) {
        const int d = d0 + ty + 8 * i;
        t[ty + 8 * i][tx] = z[(b * 256 + d) * 1024 + hw0 + tx];
    }
    __syncthreads();
#pragma unroll
    for (int i = 0; i < 4; i++) {
        const int hw = hw0 + ty + 8 * i;
        const float v = t[tx][ty + 8 * i];
        const size_t o = (size_t)(b * 1024 + hw) * DIM + d0 + tx;
        zf[o] = v;
        zb[o] = f2bf(v);
    }
}

// ---------------- emb -> eb bf16 + enorm; also zero worklist counter ----------------
__global__ __launch_bounds__(256) void k_eprep(const float* __restrict__ emb,
                                               unsigned short* __restrict__ eb,
                                               float* __restrict__ enorm,
                                               int* __restrict__ gcnt) {
    if (blockIdx.x == 0 && threadIdx.x == 0) gcnt[0] = 0;
    const int wave = threadIdx.x >> 6, lane = threadIdx.x & 63;
    const int row = blockIdx.x * 4 + wave;
    const float4 v = *(const float4*)(emb + (size_t)row * DIM + lane * 4);
    ushort4 o;
    o.x = f2bf(v.x); o.y = f2bf(v.y); o.z = f2bf(v.z); o.w = f2bf(v.w);
    *(ushort4*)(eb + (size_t)row * DIM + lane * 4) = o;
    float s = v.x * v.x + v.y * v.y + v.z * v.z + v.w * v.w;
#pragma unroll
    for (int m = 1; m < 64; m <<= 1) s += __shfl_xor(s, m, 64);
    if (lane == 0) enorm[row] = s;
}

// ---------------- rownorm over zf ----------------
__global__ __launch_bounds__(256) void k_rownorm(const float* __restrict__ src,
                                                 float* __restrict__ dst) {
    const int wave = threadIdx.x >> 6, lane = threadIdx.x & 63;
    const int row = blockIdx.x * 4 + wave;
    const float4 v = *(const float4*)(src + (size_t)row * DIM + lane * 4);
    float s = v.x * v.x + v.y * v.y + v.z * v.z + v.w * v.w;
#pragma unroll
    for (int m = 1; m < 64; m <<= 1) s += __shfl_xor(s, m, 64);
    if (lane == 0) dst[row] = s;
}

// ---------------- LDS-free bf16 MFMA scoring, register ping-pong prefetch ----------------
// Block: 64 rows x 256 cols; wave wc covers 64 rows x 64 cols.
// Group g = by*16 + wc*4 + (m15>>2): codes by*256 + wc*64 + ct*16 + (m15>>2)*4 + l
// pvalh[row][g] = fp16( min over the group's 16 codes of (en - 2*dot_bf16) )
__global__ __launch_bounds__(256, 2) void k_score(
        const unsigned short* __restrict__ zb, const unsigned short* __restrict__ eb,
        const float* __restrict__ enorm, unsigned short* __restrict__ pvalh) {
    __shared__ unsigned short sm[64 * 16];   // 2 KB
    const int row0 = blockIdx.x * 64;
    const int col0 = blockIdx.y * 256;
    const int t = threadIdx.x;
    const int lane = t & 63;
    const int wc = t >> 6;
    const int q = lane >> 4, m15 = lane & 15;

    f4v acc[4][4];
#pragma unroll
    for (int rt = 0; rt < 4; rt++)
#pragma unroll
        for (int ct = 0; ct < 4; ct++) acc[rt][ct] = (f4v){0.f, 0.f, 0.f, 0.f};

    const unsigned short* a0 = zb + (size_t)(row0 + m15) * DIM + q * 8;
    const unsigned short* b0 = eb + (size_t)(col0 + wc * 64 + m15) * DIM + q * 8;

    bf8v af[2][4], bfv[2][4];
    // preload iteration 0 into buffer 0
#pragma unroll
    for (int rt = 0; rt < 4; rt++) af[0][rt] = *(const bf8v*)(a0 + (size_t)rt * 16 * DIM);
#pragma unroll
    for (int ct = 0; ct < 4; ct++) bfv[0][ct] = *(const bf8v*)(b0 + (size_t)ct * 16 * DIM);

#pragma unroll
    for (int it = 0; it < 8; it++) {
        const int cur = it & 1, nxt = cur ^ 1;
        if (it < 7) {
            const int kk = (it + 1) * 32;
#pragma unroll
            for (int rt = 0; rt < 4; rt++)
                af[nxt][rt] = *(const bf8v*)(a0 + (size_t)rt * 16 * DIM + kk);
#pragma unroll
            for (int ct = 0; ct < 4; ct++)
                bfv[nxt][ct] = *(const bf8v*)(b0 + (size_t)ct * 16 * DIM + kk);
        }
#pragma unroll
        for (int rt = 0; rt < 4; rt++)
#pragma unroll
            for (int ct = 0; ct < 4; ct++)
                acc[rt][ct] = __builtin_amdgcn_mfma_f32_16x16x32_bf16(af[cur][rt], bfv[cur][ct], acc[rt][ct], 0, 0, 0);
    }

    // epilogue: s = en - 2*dot (approx, filter-only); fp32 group-min, fp16 store
    float en_l[4];
#pragma unroll
    for (int ct = 0; ct < 4; ct++) en_l[ct] = enorm[col0 + wc * 64 + ct * 16 + m15];

    const int g_local = wc * 4 + (m15 >> 2);
#pragma unroll
    for (int rt = 0; rt < 4; rt++) {
        float sv[4];
#pragma unroll
        for (int j = 0; j < 4; j++) {
            float s = fmaf(-2.f, acc[rt][0][j], en_l[0]);
#pragma unroll
            for (int ct = 1; ct < 4; ct++)
                s = fminf(s, fmaf(-2.f, acc[rt][ct][j], en_l[ct]));
            sv[j] = s;
        }
        // butterfly over l = m15&3 (xor 1, 2)
#pragma unroll
        for (int m = 1; m <= 2; m <<= 1)
#pragma unroll
            for (int j = 0; j < 4; j++)
                sv[j] = fminf(sv[j], __shfl_xor(sv[j], m, 64));
        if ((m15 & 3) == 0) {
            const int rbase = rt * 16 + q * 4;
#pragma unroll
            for (int j = 0; j < 4; j++)
                sm[(rbase + j) * 16 + g_local] = __half_as_ushort(__float2half_rn(sv[j]));
        }
    }
    __syncthreads();
    if (t < 128) {
        const uint4 v = *(const uint4*)&sm[t * 8];
        *(uint4*)&pvalh[(size_t)(row0 + (t >> 1)) * 1024 + blockIdx.y * 16 + (t & 1) * 8] = v;
    }
}

// ---------------- flag: per row, min over 1024 group-mins; append flagged to worklist ------------
__global__ __launch_bounds__(256) void k_flag(const unsigned short* __restrict__ pvalh,
                                              unsigned long long* __restrict__ best64,
                                              int* __restrict__ wl, int* __restrict__ gcnt) {
    const int row = blockIdx.x;
    const int t = threadIdx.x;
    const int lane = t & 63, w = t >> 6;
    __shared__ float wmin[4];
    __shared__ int lcnt, lbase;
    __shared__ int llist[1024];
    if (t == 0) { lcnt = 0; best64[row] = 0xFFFFFFFFFFFFFFFFULL; }
    const __half* p = (const __half*)(pvalh + (size_t)row * 1024 + t * 4);
    float v[4];
#pragma unroll
    for (int k = 0; k < 4; k++) v[k] = __half2float(p[k]);
    float mn = fminf(fminf(v[0], v[1]), fminf(v[2], v[3]));
#pragma unroll
    for (int m = 1; m < 64; m <<= 1) mn = fminf(mn, __shfl_xor(mn, m, 64));
    if (lane == 0) wmin[w] = mn;
    __syncthreads();
    const float g = fminf(fminf(wmin[0], wmin[1]), fminf(wmin[2], wmin[3])) + MARGIN;
#pragma unroll
    for (int k = 0; k < 4; k++) {
        if (v[k] <= g) {
            const int pos = atomicAdd(&lcnt, 1);
            llist[pos] = (row << 10) | (t * 4 + k);
        }
    }
    __syncthreads();
    if (t == 0) lbase = atomicAdd(gcnt, lcnt);
    __syncthreads();
    for (int i = t; i < lcnt; i += 256) {
        const int d = lbase + i;
        if (d < WLCAP) wl[d] = llist[i];
    }
}

// ---------------- rescore: exact fp32 re-score of flagged 16-code (strided) groups --------------
__global__ __launch_bounds__(256) void k_rescore(
        const float* __restrict__ zf, const float* __restrict__ emb,
        const float* __restrict__ znorm, const float* __restrict__ enorm,
        const int* __restrict__ wl, const int* __restrict__ gcnt,
        unsigned long long* __restrict__ best64) {
    const int count = min(gcnt[0], WLCAP);
    const int t = threadIdx.x;
    const int lane16 = t & 15, codei = t >> 4;
    for (int item = blockIdx.x; item < count; item += gridDim.x) {
        const int e = wl[item];
        const int row = e >> 10, g = e & 1023;
        // group membership: codes = (g>>4)*256 + ((g>>2)&3)*64 + ct*16 + (g&3)*4 + l
        const int cbase = ((g >> 4) << 8) + (((g >> 2) & 3) << 6) + ((g & 3) << 2);
        const int code = cbase + ((codei >> 2) << 4) + (codei & 3);
        const float* zp = zf + (size_t)row * DIM + lane16 * 16;
        const float* ep = emb + (size_t)code * DIM + lane16 * 16;
        float d = 0.f;
#pragma unroll
        for (int k = 0; k < 16; k += 4) {
            const float4 ev = *(const float4*)(ep + k);
            const float4 zv = *(const float4*)(zp + k);
            d = fmaf(zv.x, ev.x, d);
            d = fmaf(zv.y, ev.y, d);
            d = fmaf(zv.z, ev.z, d);
            d = fmaf(zv.w, ev.w, d);
        }
#pragma unroll
        for (int m = 1; m <= 8; m <<= 1) d += __shfl_xor(d, m, 64);
        if (lane16 == 0) {
            const float tt = znorm[row] + enorm[code];
            const float s = tt - 2.0f * d;   // exact fp32 semantics
            const unsigned long long key =
                ((unsigned long long)__float_as_uint(s) << 32) | (unsigned)code;
            atomicMin(&best64[row], key);
        }
    }
}

// ---------------- out_idx from best64 ----------------
__global__ __launch_bounds__(256) void k_finalidx(const unsigned long long* __restrict__ best64,
                                                  float* __restrict__ out_idx) {
    const int i = blockIdx.x * 256 + threadIdx.x;
    out_idx[i] = (float)(unsigned)(best64[i] & 0xFFFFFFFFULL);
}

// ---------------- gather z_q (NCHW) + loss partials ----------------
__global__ __launch_bounds__(256) void k_gather(const float* __restrict__ emb,
                                                const float* __restrict__ zf,
                                                const unsigned long long* __restrict__ best64,
                                                float* __restrict__ zq,
                                                float* __restrict__ loss_part) {
    __shared__ float t[32][33];
    const int hw0 = blockIdx.x * 32;
    const int c0  = blockIdx.y * 32;
    const int b   = blockIdx.z;
    const int tx = threadIdx.x & 31, ty = threadIdx.x >> 5;
    float lsum = 0.f;
#pragma unroll
    for (int i = 0; i < 4; i++) {
        const int hh = ty + 8 * i;
        const int n = b * 1024 + hw0 + hh;
        const int id = (int)(best64[n] & 0xFFFFFFFFULL);
        const float q = emb[(size_t)id * DIM + c0 + tx];
        const float zv = zf[(size_t)n * DIM + c0 + tx];
        const float d = q - zv;
        lsum += d * d;
        t[hh][tx] = q;
    }
    __syncthreads();
#pragma unroll
    for (int i = 0; i < 4; i++) {
        const int c = c0 + ty + 8 * i;
        zq[(size_t)(b * 256 + c) * 1024 + hw0 + tx] = t[tx][ty + 8 * i];
    }
#pragma unroll
    for (int m = 1; m < 64; m <<= 1) lsum += __shfl_xor(lsum, m, 64);
    __shared__ float wsum[4];
    const int lane = threadIdx.x & 63, w = threadIdx.x >> 6;
    if (lane == 0) wsum[w] = lsum;
    __syncthreads();
    if (threadIdx.x == 0) {
        const int bid = (blockIdx.z * gridDim.y + blockIdx.y) * gridDim.x + blockIdx.x;
        loss_part[bid] = wsum[0] + wsum[1] + wsum[2] + wsum[3];
    }
}

// ---------------- finalize loss ----------------
__global__ __launch_bounds__(256) void k_final(const float* __restrict__ loss_part,
                                               float* __restrict__ out_loss) {
    float s = 0.f;
    for (int i = threadIdx.x; i < 2048; i += 256) s += loss_part[i];
#pragma unroll
    for (int m = 1; m < 64; m <<= 1) s += __shfl_xor(s, m, 64);
    __shared__ float wsum[4];
    const int lane = threadIdx.x & 63, w = threadIdx.x >> 6;
    if (lane == 0) wsum[w] = s;
    __syncthreads();
    if (threadIdx.x == 0) {
        out_loss[0] = 1.25f * (wsum[0] + wsum[1] + wsum[2] + wsum[3]) / 2097152.0f;
    }
}

extern "C" void kernel_launch(void* const* d_in, const int* in_sizes, int n_in,
                              void* d_out, int out_size, void* d_ws, size_t ws_size,
                              hipStream_t stream) {
    const float* z   = (const float*)d_in[0];   // [8,256,32,32]
    const float* emb = (const float*)d_in[1];   // [16384,256]
    float* out = (float*)d_out;
    float* ws  = (float*)d_ws;

    // ws layout (float-slot offsets):
    float*              zf    = ws;                                   // 2,097,152  (8 MB)
    unsigned short*     pvalh = (unsigned short*)(ws + 2097152);      // 8M halves  (16 MB)
    unsigned short*     zb    = (unsigned short*)(ws + 6291456);      // 2M halves  (4 MB)
    unsigned short*     eb    = (unsigned short*)(ws + 7340032);      // 4M halves  (8 MB)
    float*              enorm = ws + 9437184;                         // 16,384
    float*              znorm = ws + 9453568;                         // 8,192
    unsigned long long* best64= (unsigned long long*)(ws + 9461760);  // 8192 × 8 B
    int*                wl    = (int*)(ws + 9478144);                 // 262,144
    int*                gcnt  = (int*)(ws + 9740288);                 // 8
    float*              lossp = ws + 9740296;                         // 2,048
    // total ≈ 39 MB

    float* zq       = out;                   // [8,256,32,32] NCHW
    float* out_loss = out + 2097152;         // scalar
    float* out_idx  = out + 2097153;         // [8192] as float32

    k_zprep<<<dim3(32, 8, 8), 256, 0, stream>>>(z, zf, zb);
    k_eprep<<<dim3(4096), 256, 0, stream>>>(emb, eb, enorm, gcnt);
    k_rownorm<<<dim3(2048), 256, 0, stream>>>(zf, znorm);
    k_score<<<dim3(128, 64), 256, 0, stream>>>(zb, eb, enorm, pvalh);
    k_flag<<<dim3(8192), 256, 0, stream>>>(pvalh, best64, wl, gcnt);
    k_rescore<<<dim3(2048), 256, 0, stream>>>(zf, emb, znorm, enorm, wl, gcnt, best64);
    k_finalidx<<<dim3(32), 256, 0, stream>>>(best64, out_idx);
    k_gather<<<dim3(32, 8, 8), 256, 0, stream>>>(emb, zf, best64, zq, lossp);
    k_final<<<1, 256, 0, stream>>>(lossp, out_loss);
}